// Round 12
// baseline (60.716 us; speedup 1.0000x reference)
//
#include <hip/hip_runtime.h>

// Reference: x[65536][1024] f32, weight[128][1024] f32 -> out[128][1024] f32.
// out[i,j] = exp(s_i*t_j)/det_i; s=rowsum(w), t=colsum(w), c=colsum(x),
// det_i = sum_k exp(s_i*c_k).  Mandatory traffic: 256 MiB cold read of x.
//
// Wave-contention ladder (waves/CU -> total us): 32 -> 57.4, 16 -> 54.2,
// 8 -> 50.5 (r10), 8-in-one-block -> 51.9 (r11, worse). This round: 4
// waves/CU, 1 block/CU, 1 MiB contiguous slab per block, 8x16B in flight
// per thread (32 KiB/CU in flight, ~3x latency-hiding requirement).
constexpr int N_ROWS = 65536;
constexpr int D      = 1024;
constexpr int CH     = 128;
constexpr int GRID   = 256;              // 1 block/CU
constexpr int BLOCK  = 256;              // 4 waves/CU
constexpr int RPB    = N_ROWS / GRID;    // 256 rows per block
constexpr int PROWS  = GRID;             // one partial row per block

typedef float f32x4 __attribute__((ext_vector_type(4)));

// ---------------------------------------------------------------------------
// K1: block b owns rows [b*256, (b+1)*256) — contiguous 1 MiB slab.
// 256 thr x f32x4 = one 1024-col row per load; per outer iter (32 total):
// 8 rows in flight, 8 independent accumulators. Thread tid owns columns
// 4*tid..4*tid+3. VGPR ~40 (well under the 64 needed for this occupancy).
// ---------------------------------------------------------------------------
__global__ __launch_bounds__(BLOCK, 4) void colsum_partial_kernel(
    const float* __restrict__ x, float* __restrict__ partial) {
    const int tid  = threadIdx.x;          // 0..255
    const size_t b = blockIdx.x;
    const f32x4* __restrict__ p =
        reinterpret_cast<const f32x4*>(x) + b * (size_t)RPB * 256 + tid;

    f32x4 a0 = 0.f, a1 = 0.f, a2 = 0.f, a3 = 0.f;
    f32x4 a4 = 0.f, a5 = 0.f, a6 = 0.f, a7 = 0.f;
    for (int i = 0; i < RPB / 8; ++i) {    // 32 iters
        const f32x4* q = p + (size_t)i * 8 * 256;   // 8 rows per iter
        a0 += q[0 * 256]; a1 += q[1 * 256]; a2 += q[2 * 256]; a3 += q[3 * 256];
        a4 += q[4 * 256]; a5 += q[5 * 256]; a6 += q[6 * 256]; a7 += q[7 * 256];
    }
    f32x4 o = ((a0 + a1) + (a2 + a3)) + ((a4 + a5) + (a6 + a7));
    reinterpret_cast<f32x4*>(partial)[b * 256 + tid] = o;
}

// ---------------------------------------------------------------------------
// K2: blocks 0..127 reduce partial[PROWS][1024] -> c[1024] (8 cols/block,
//     32 row-groups x 8 rows); blocks 128..255: column-sum weight -> t.
// Fixed order -> deterministic.
// ---------------------------------------------------------------------------
__global__ __launch_bounds__(256) void reduce_ct_kernel(
    const float* __restrict__ partial,
    const float* __restrict__ w,
    float* __restrict__ c, float* __restrict__ t) {
    const int b     = blockIdx.x;
    const int tid   = threadIdx.x;
    const int colin = tid & 7;
    const int grp   = tid >> 3;   // 0..31
    __shared__ float red[32][8];

    float acc = 0.f;
    int col;
    if (b < 128) {
        col = b * 8 + colin;
        const int cpg = PROWS / 32;    // 8
        const float* __restrict__ p = partial + (size_t)(grp * cpg) * D + col;
        #pragma unroll
        for (int ch = 0; ch < cpg; ++ch) acc += p[(size_t)ch * D];
    } else {
        col = (b - 128) * 8 + colin;
        const float* __restrict__ p = w + (size_t)(grp * (CH / 32)) * D + col;
        #pragma unroll
        for (int r = 0; r < CH / 32; ++r) acc += p[(size_t)r * D];
    }
    red[grp][colin] = acc;
    __syncthreads();
    for (int s = 16; s > 0; s >>= 1) {
        if (grp < s) red[grp][colin] += red[grp + s][colin];
        __syncthreads();
    }
    if (grp == 0) {
        if (b < 128) c[col] = red[0][colin];
        else         t[col] = red[0][colin];
    }
}

// ---------------------------------------------------------------------------
// K3: one block per output row i; shfl-butterfly reductions.
// ---------------------------------------------------------------------------
__global__ __launch_bounds__(256) void out_kernel(
    const float* __restrict__ w, const float* __restrict__ c,
    const float* __restrict__ t, float* __restrict__ out) {
    const int i    = blockIdx.x;
    const int tid  = threadIdx.x;
    const int wid  = tid >> 6;
    const int lane = tid & 63;
    __shared__ float red[8];

    float4 wv = reinterpret_cast<const float4*>(w + (size_t)i * D)[tid];
    float sv = (wv.x + wv.y) + (wv.z + wv.w);
    #pragma unroll
    for (int m = 32; m > 0; m >>= 1) sv += __shfl_xor(sv, m, 64);
    if (lane == 0) red[wid] = sv;
    __syncthreads();
    const float s_i = (red[0] + red[1]) + (red[2] + red[3]);

    float4 cv = reinterpret_cast<const float4*>(c)[tid];
    float ev = (expf(s_i * cv.x) + expf(s_i * cv.y)) +
               (expf(s_i * cv.z) + expf(s_i * cv.w));
    #pragma unroll
    for (int m = 32; m > 0; m >>= 1) ev += __shfl_xor(ev, m, 64);
    if (lane == 0) red[4 + wid] = ev;
    __syncthreads();
    const float inv_det = 1.0f / ((red[4] + red[5]) + (red[6] + red[7]));

    float4 tv = reinterpret_cast<const float4*>(t)[tid];
    float4 o;
    o.x = expf(s_i * tv.x) * inv_det;
    o.y = expf(s_i * tv.y) * inv_det;
    o.z = expf(s_i * tv.z) * inv_det;
    o.w = expf(s_i * tv.w) * inv_det;
    reinterpret_cast<float4*>(out + (size_t)i * D)[tid] = o;
}

// ---------------------------------------------------------------------------
// launch
// ---------------------------------------------------------------------------
extern "C" void kernel_launch(void* const* d_in, const int* in_sizes, int n_in,
                              void* d_out, int out_size, void* d_ws, size_t ws_size,
                              hipStream_t stream) {
    const float* x = (const float*)d_in[0];
    const float* w = (const float*)d_in[1];
    float* out = (float*)d_out;

    char* ws = (char*)d_ws;
    float* c       = (float*)(ws);
    float* t       = (float*)(ws + 4096);
    float* partial = (float*)(ws + 8192);   // PROWS*1024 floats = 1 MiB

    colsum_partial_kernel<<<GRID, BLOCK, 0, stream>>>(x, partial);
    reduce_ct_kernel<<<256, 256, 0, stream>>>(partial, w, c, t);
    out_kernel<<<CH, 256, 0, stream>>>(w, c, t, out);
}

// Round 13
// 50.001 us; speedup vs baseline: 1.2143x; 1.2143x over previous
//
#include <hip/hip_runtime.h>

// Reference: x[65536][1024] f32, weight[128][1024] f32 -> out[128][1024] f32.
// out[i,j] = exp(s_i*t_j)/det_i; s=rowsum(w), t=colsum(w), c=colsum(x),
// det_i = sum_k exp(s_i*c_k).  Mandatory traffic: 256 MiB cold read of x.
//
// REVERT to r10 = empirical optimum. Wave ladder (waves/CU -> total us):
// 32 -> 57.4, 16 -> 54.2, **8 -> 50.5**, 4 -> 60.7. 8 waves/CU x 8 KiB
// in flight saturates the CU's HBM share without fragmenting DRAM
// row-buffer locality. K1 ~= 43.5 us = 6.2 TB/s cold read (probe ceiling
// 6.5); tails ~7 us.
constexpr int N_ROWS = 65536;
constexpr int D      = 1024;
constexpr int CH     = 128;
constexpr int NCHUNK = 512;   // 2 blocks/CU x 4 waves = 8 waves/CU

typedef float f32x4 __attribute__((ext_vector_type(4)));

// ---------------------------------------------------------------------------
// K1: block b owns rows [b*rpb, (b+1)*rpb) — contiguous 512 KiB slab at
// nchunk=512 (rpb=128). Per outer iter (16): 8 rows (32 KiB/block) in
// flight, 8 independent accumulators. Thread tid owns cols 4*tid..4*tid+3.
// ---------------------------------------------------------------------------
__global__ __launch_bounds__(256, 4) void colsum_partial_kernel(
    const float* __restrict__ x, float* __restrict__ partial, int nchunk) {
    const int tid   = threadIdx.x;
    const size_t b  = blockIdx.x;
    const int rpb   = N_ROWS / nchunk;       // 128
    const f32x4* __restrict__ p =
        reinterpret_cast<const f32x4*>(x) + b * (size_t)rpb * 256 + tid;

    f32x4 a0 = 0.f, a1 = 0.f, a2 = 0.f, a3 = 0.f;
    f32x4 a4 = 0.f, a5 = 0.f, a6 = 0.f, a7 = 0.f;
    for (int i = 0; i < rpb / 8; ++i) {
        const f32x4* q = p + (size_t)i * 8 * 256;
        a0 += q[0 * 256]; a1 += q[1 * 256]; a2 += q[2 * 256]; a3 += q[3 * 256];
        a4 += q[4 * 256]; a5 += q[5 * 256]; a6 += q[6 * 256]; a7 += q[7 * 256];
    }
    f32x4 o = ((a0 + a1) + (a2 + a3)) + ((a4 + a5) + (a6 + a7));
    reinterpret_cast<f32x4*>(partial)[b * 256 + tid] = o;
}

// ---------------------------------------------------------------------------
// K2: blocks 0..127 reduce partial[nchunk][1024] -> c[1024] (8 cols/block,
//     32 row-groups x 16 rows); blocks 128..255: column-sum weight -> t.
// Fixed order -> deterministic.
// ---------------------------------------------------------------------------
__global__ __launch_bounds__(256) void reduce_ct_kernel(
    const float* __restrict__ partial, int nchunk,
    const float* __restrict__ w,
    float* __restrict__ c, float* __restrict__ t) {
    const int b     = blockIdx.x;
    const int tid   = threadIdx.x;
    const int colin = tid & 7;
    const int grp   = tid >> 3;   // 0..31
    __shared__ float red[32][8];

    float acc = 0.f;
    int col;
    if (b < 128) {
        col = b * 8 + colin;
        const int cpg = nchunk >> 5;   // 16 @ nchunk=512
        const float* __restrict__ p = partial + (size_t)(grp * cpg) * D + col;
        #pragma unroll 8
        for (int ch = 0; ch < cpg; ++ch) acc += p[(size_t)ch * D];
    } else {
        col = (b - 128) * 8 + colin;
        const float* __restrict__ p = w + (size_t)(grp * (CH / 32)) * D + col;
        #pragma unroll
        for (int r = 0; r < CH / 32; ++r) acc += p[(size_t)r * D];
    }
    red[grp][colin] = acc;
    __syncthreads();
    for (int s = 16; s > 0; s >>= 1) {
        if (grp < s) red[grp][colin] += red[grp + s][colin];
        __syncthreads();
    }
    if (grp == 0) {
        if (b < 128) c[col] = red[0][colin];
        else         t[col] = red[0][colin];
    }
}

// ---------------------------------------------------------------------------
// K3: one block per output row i; shfl-butterfly reductions.
// ---------------------------------------------------------------------------
__global__ __launch_bounds__(256) void out_kernel(
    const float* __restrict__ w, const float* __restrict__ c,
    const float* __restrict__ t, float* __restrict__ out) {
    const int i    = blockIdx.x;
    const int tid  = threadIdx.x;
    const int wid  = tid >> 6;
    const int lane = tid & 63;
    __shared__ float red[8];

    float4 wv = reinterpret_cast<const float4*>(w + (size_t)i * D)[tid];
    float sv = (wv.x + wv.y) + (wv.z + wv.w);
    #pragma unroll
    for (int m = 32; m > 0; m >>= 1) sv += __shfl_xor(sv, m, 64);
    if (lane == 0) red[wid] = sv;
    __syncthreads();
    const float s_i = (red[0] + red[1]) + (red[2] + red[3]);

    float4 cv = reinterpret_cast<const float4*>(c)[tid];
    float ev = (expf(s_i * cv.x) + expf(s_i * cv.y)) +
               (expf(s_i * cv.z) + expf(s_i * cv.w));
    #pragma unroll
    for (int m = 32; m > 0; m >>= 1) ev += __shfl_xor(ev, m, 64);
    if (lane == 0) red[4 + wid] = ev;
    __syncthreads();
    const float inv_det = 1.0f / ((red[4] + red[5]) + (red[6] + red[7]));

    float4 tv = reinterpret_cast<const float4*>(t)[tid];
    float4 o;
    o.x = expf(s_i * tv.x) * inv_det;
    o.y = expf(s_i * tv.y) * inv_det;
    o.z = expf(s_i * tv.z) * inv_det;
    o.w = expf(s_i * tv.w) * inv_det;
    reinterpret_cast<float4*>(out + (size_t)i * D)[tid] = o;
}

// ---------------------------------------------------------------------------
// launch
// ---------------------------------------------------------------------------
extern "C" void kernel_launch(void* const* d_in, const int* in_sizes, int n_in,
                              void* d_out, int out_size, void* d_ws, size_t ws_size,
                              hipStream_t stream) {
    const float* x = (const float*)d_in[0];
    const float* w = (const float*)d_in[1];
    float* out = (float*)d_out;

    char* ws = (char*)d_ws;
    float* c       = (float*)(ws);
    float* t       = (float*)(ws + 4096);
    float* partial = (float*)(ws + 8192);

    int nchunk = NCHUNK;
    while (nchunk > 32 && (size_t)nchunk * D * sizeof(float) + 8192 > ws_size)
        nchunk >>= 1;

    colsum_partial_kernel<<<nchunk, 256, 0, stream>>>(x, partial, nchunk);
    reduce_ct_kernel<<<256, 256, 0, stream>>>(partial, nchunk, w, c, t);
    out_kernel<<<CH, 256, 0, stream>>>(w, c, t, out);
}